// Round 5
// baseline (129.595 us; speedup 1.0000x reference)
//
#include <hip/hip_runtime.h>
#include <math.h>

#ifndef M_PI
#define M_PI 3.14159265358979323846
#endif

#define LUT_N 4096
#define WPB 4   // waves per block
#define TROWS 4 // rows per LDS tile (one per wave)

// nearest-entry LUT cos, replicating jnp round-half-even + float mod semantics
__device__ __forceinline__ float lut_cos(float theta) {
    const float IDX_SCALE = (float)((double)LUT_N / (2.0 * M_PI)); // fl(4096/2pi)
    const float STEP = (float)((2.0 * M_PI) / (double)LUT_N);      // fl(2pi/4096)
    float x = theta * IDX_SCALE;
    int i = (int)rintf(x);     // round-half-even, matches jnp.round/np.round
    i &= (LUT_N - 1);          // == Python mod for pow2 in two's complement
    return cosf((float)i * STEP);
}

__global__ void qgen_kernel(const float* __restrict__ cur_r,
                            const float* __restrict__ cur_i,
                            const float* __restrict__ w_q,
                            const float* __restrict__ b_q,
                            const float* __restrict__ t_ptr,
                            float* __restrict__ q_out,
                            int B, int D) {
    int idx = blockIdx.x * blockDim.x + threadIdx.x;
    int twoD = 2 * D;
    if (idx >= B * twoD) return;
    int b = idx / twoD;
    int c = idx - b * twoD;
    int col = (c < D) ? c : c - D;
    const float* src = (c < D) ? cur_r : cur_i;
    float v = src[(size_t)b * D + col];
    float t_phi = t_ptr[0] * 1.61803398874989484820f;  // f32(PHI), f32 multiply
    float wl = 1.0f + fabsf(w_q[col]);
    float theta = v / wl + b_q[col] + t_phi;           // same op order as ref
    q_out[idx] = lut_cos(theta);
}

typedef const __attribute__((address_space(1))) unsigned int guint;
typedef __attribute__((address_space(3))) unsigned int suint;

// DMA one full 4096-f32 row (real half + imag half) into LDS, linearly.
// Each call: 16x global_load_lds_dwordx4 (1 KB each), no VGPR round-trip.
// LDS dest is wave-uniform base; HW adds lane*16.
__device__ __forceinline__ void stage_row(const float* __restrict__ hr_row,
                                          const float* __restrict__ hi_row,
                                          float* lds_row, int lane) {
#pragma unroll
    for (int c = 0; c < 8; ++c)
        __builtin_amdgcn_global_load_lds(
            (guint*)(const void*)(hr_row + c * 256 + lane * 4),
            (suint*)(void*)(lds_row + c * 256), 16, 0, 0);
#pragma unroll
    for (int c = 0; c < 8; ++c)
        __builtin_amdgcn_global_load_lds(
            (guint*)(const void*)(hi_row + c * 256 + lane * 4),
            (suint*)(void*)(lds_row + 2048 + c * 256), 16, 0, 0);
}

// Flash with LDS DMA staging: block = 4 waves, tile = 4 rows (wave w owns
// row w of each tile). stage(k+1) issues before processing tile k; the
// single per-tile __syncthreads drains vmcnt AFTER the compute window.
// Online softmax per wave (defer-max), 4-wave merge at the end.
// Requires 2D == 4096 and rows_blk % TROWS == 0.
__global__ __launch_bounds__(256, 1) void flash_kernel(
    const float* __restrict__ hist_r,
    const float* __restrict__ hist_i,
    const float* __restrict__ q_ws,
    float* __restrict__ r_ws,
    float* __restrict__ ml_ws,
    int H, int S) {
    const int t = threadIdx.x;
    const int lane = t & 63;
    const int wv = t >> 6;                 // 0..3
    const int b = blockIdx.x / S;
    const int s = blockIdx.x - b * S;
    const int rows_blk = H / S;            // 64
    const int NT = rows_blk / TROWS;       // 16 tiles

    __shared__ float buf[2][TROWS][4096];  // 128 KB double-buffered tile
    __shared__ float sm[WPB], sl[WPB];

    // wave w's first row: global row index b*H + s*rows_blk + w (step TROWS)
    const size_t row0 = (size_t)b * H + (size_t)s * rows_blk + wv;
    const float* hr_w = hist_r + row0 * 2048;
    const float* hi_w = hist_i + row0 * 2048;

    // q in registers (16 float4 per lane)
    const float4* q4 = (const float4*)q_ws + (size_t)b * 1024;
    float4 qv[16];
#pragma unroll
    for (int j = 0; j < 16; ++j) qv[j] = q4[j * 64 + lane];

    float4 rv[16];
#pragma unroll
    for (int j = 0; j < 16; ++j) rv[j] = make_float4(0.f, 0.f, 0.f, 0.f);
    float m0 = -INFINITY, l = 0.f;
    const float inv_scale = 1.0f / 64.0f;  // 1/sqrt(2*2048), exact

    // prologue: stage tile 0
    stage_row(hr_w, hi_w, &buf[0][wv][0], lane);
    __syncthreads();

    for (int kt = 0; kt < NT; ++kt) {
        // issue next tile's DMA before touching current tile
        if (kt + 1 < NT)
            stage_row(hr_w + (size_t)(kt + 1) * TROWS * 2048,
                      hi_w + (size_t)(kt + 1) * TROWS * 2048,
                      &buf[(kt + 1) & 1][wv][0], lane);

        // process row wv of tile kt from LDS
        const float4* krow = (const float4*)&buf[kt & 1][wv][0];
        float4 kv[16];
#pragma unroll
        for (int j = 0; j < 16; ++j) kv[j] = krow[j * 64 + lane];

        float p = 0.f;
#pragma unroll
        for (int j = 0; j < 16; ++j)
            p += qv[j].x * kv[j].x + qv[j].y * kv[j].y +
                 qv[j].z * kv[j].z + qv[j].w * kv[j].w;
#pragma unroll
        for (int off = 32; off; off >>= 1) p += __shfl_xor(p, off);
        float sc = p * inv_scale;          // wave-uniform

        float d = sc - m0;
        float w;
        if (d > 8.0f) {                    // rare, wave-uniform; first row: d=+inf
            float corr = __expf(-d);       // first row: exp(-inf) = 0
            l *= corr;
#pragma unroll
            for (int j = 0; j < 16; ++j) {
                rv[j].x *= corr; rv[j].y *= corr;
                rv[j].z *= corr; rv[j].w *= corr;
            }
            m0 = sc;
            w = 1.0f;
        } else {
            w = __expf(d);                 // bounded by e^8
        }
        l += w;
#pragma unroll
        for (int j = 0; j < 16; ++j) {
            rv[j].x = fmaf(w, kv[j].x, rv[j].x);
            rv[j].y = fmaf(w, kv[j].y, rv[j].y);
            rv[j].z = fmaf(w, kv[j].z, rv[j].z);
            rv[j].w = fmaf(w, kv[j].w, rv[j].w);
        }

        // drains vmcnt (next tile arrived) + protects buf[kt&1] WAR
        __syncthreads();
    }

    // ---- end-of-kernel block merge (reuse buf[0] as scratch) ----
    if (lane == 0) { sm[wv] = m0; sl[wv] = l; }
    __syncthreads();
    float M = fmaxf(fmaxf(sm[0], sm[1]), fmaxf(sm[2], sm[3]));
    float Lb = sl[0] * __expf(sm[0] - M) + sl[1] * __expf(sm[1] - M) +
               sl[2] * __expf(sm[2] - M) + sl[3] * __expf(sm[3] - M);
    float scale = __expf(m0 - M);          // per-wave rescale to block max

    float4* sred = (float4*)&buf[0][0][0];
    for (int w = 0; w < WPB; ++w) {
        if (wv == w) {
#pragma unroll
            for (int j = 0; j < 16; ++j) {
                int idx = j * 64 + lane;
                float4 v = (w == 0) ? make_float4(0.f, 0.f, 0.f, 0.f) : sred[idx];
                v.x = fmaf(scale, rv[j].x, v.x);
                v.y = fmaf(scale, rv[j].y, v.y);
                v.z = fmaf(scale, rv[j].z, v.z);
                v.w = fmaf(scale, rv[j].w, v.w);
                sred[idx] = v;
            }
        }
        __syncthreads();
    }

    float4* ro = (float4*)r_ws + (size_t)blockIdx.x * 1024;
#pragma unroll
    for (int k = 0; k < 4; ++k) ro[t + 256 * k] = sred[t + 256 * k];
    if (t == 0) {
        ml_ws[2 * (size_t)blockIdx.x] = M;
        ml_ws[2 * (size_t)blockIdx.x + 1] = Lb;
    }
}

// grid = B * (2D/256) blocks; each thread owns one output column.
__global__ void combine_kernel(const float* __restrict__ r_ws,
                               const float* __restrict__ ml_ws,
                               const float* __restrict__ ema,
                               const float* __restrict__ alpha_ptr,
                               float* __restrict__ out,
                               int D, int S) {
    const int twoD = 2 * D;
    const int nc = twoD / 256;
    const int b = blockIdx.x / nc;
    const int cb = blockIdx.x - b * nc;
    const int c = cb * 256 + threadIdx.x;

    const float* ml = ml_ws + (size_t)b * S * 2;
    float M = -INFINITY;
    for (int s = 0; s < S; ++s) M = fmaxf(M, ml[2 * s]);
    float L = 0.f;
    for (int s = 0; s < S; ++s) L += ml[2 * s + 1] * __expf(ml[2 * s] - M);

    float acc = 0.f;
    const float* rb = r_ws + (size_t)b * S * twoD + c;
    for (int s = 0; s < S; ++s)
        acc = fmaf(__expf(ml[2 * s] - M), rb[(size_t)s * twoD], acc);

    float a = 1.0f / (1.0f + __expf(-alpha_ptr[0]));  // sigmoid(alpha)
    float retrieved = acc / L;
    size_t o = (size_t)b * twoD + c;
    out[o] = a * retrieved + (1.0f - a) * ema[o];
}

extern "C" void kernel_launch(void* const* d_in, const int* in_sizes, int n_in,
                              void* d_out, int out_size, void* d_ws, size_t ws_size,
                              hipStream_t stream) {
    const float* cur_r  = (const float*)d_in[0];
    const float* cur_i  = (const float*)d_in[1];
    const float* hist_r = (const float*)d_in[2];
    const float* hist_i = (const float*)d_in[3];
    const float* ema    = (const float*)d_in[4];
    const float* w_q    = (const float*)d_in[5];
    const float* b_q    = (const float*)d_in[6];
    const float* alpha  = (const float*)d_in[7];
    const float* t      = (const float*)d_in[8];

    const int D = in_sizes[5];                 // 2048
    const int B = in_sizes[0] / D;             // 16
    const int H = in_sizes[2] / (B * D);       // 2048
    const int twoD = 2 * D;

    float* q_ws = (float*)d_ws;
    size_t q_elems = (size_t)B * twoD;

    int S = 32;  // 512 blocks, 1 block/CU (128 KB LDS), 2 rounds
    while (S > 1) {
        size_t need = (q_elems + (size_t)B * S * twoD + (size_t)B * S * 2) * sizeof(float);
        if (need <= ws_size) break;
        S >>= 1;
    }
    float* r_ws = q_ws + q_elems;
    float* ml_ws = r_ws + (size_t)B * S * twoD;

    int qblocks = (B * twoD + 255) / 256;
    qgen_kernel<<<qblocks, 256, 0, stream>>>(cur_r, cur_i, w_q, b_q, t, q_ws, B, D);
    flash_kernel<<<B * S, 256, 0, stream>>>(hist_r, hist_i, q_ws, r_ws, ml_ws, H, S);
    combine_kernel<<<B * (twoD / 256), 256, 0, stream>>>(r_ws, ml_ws, ema, alpha,
                                                         (float*)d_out, D, S);
}

// Round 6
// 125.709 us; speedup vs baseline: 1.0309x; 1.0309x over previous
//
#include <hip/hip_runtime.h>
#include <math.h>

#ifndef M_PI
#define M_PI 3.14159265358979323846
#endif

#define LUT_N 4096
#define WVS 3    // waves per block (each fully independent)
#define DEPTH 3  // per-wave LDS ring depth (rows)

// nearest-entry LUT cos, replicating jnp round-half-even + float mod semantics
__device__ __forceinline__ float lut_cos(float theta) {
    const float IDX_SCALE = (float)((double)LUT_N / (2.0 * M_PI)); // fl(4096/2pi)
    const float STEP = (float)((2.0 * M_PI) / (double)LUT_N);      // fl(2pi/4096)
    float x = theta * IDX_SCALE;
    int i = (int)rintf(x);     // round-half-even, matches jnp.round/np.round
    i &= (LUT_N - 1);          // == Python mod for pow2 in two's complement
    return cosf((float)i * STEP);
}

__global__ void qgen_kernel(const float* __restrict__ cur_r,
                            const float* __restrict__ cur_i,
                            const float* __restrict__ w_q,
                            const float* __restrict__ b_q,
                            const float* __restrict__ t_ptr,
                            float* __restrict__ q_out,
                            int B, int D) {
    int idx = blockIdx.x * blockDim.x + threadIdx.x;
    int twoD = 2 * D;
    if (idx >= B * twoD) return;
    int b = idx / twoD;
    int c = idx - b * twoD;
    int col = (c < D) ? c : c - D;
    const float* src = (c < D) ? cur_r : cur_i;
    float v = src[(size_t)b * D + col];
    float t_phi = t_ptr[0] * 1.61803398874989484820f;  // f32(PHI), f32 multiply
    float wl = 1.0f + fabsf(w_q[col]);
    float theta = v / wl + b_q[col] + t_phi;           // same op order as ref
    q_out[idx] = lut_cos(theta);
}

typedef const __attribute__((address_space(1))) unsigned int guint;
typedef __attribute__((address_space(3))) unsigned int suint;

// DMA one full 4096-f32 row (real half + imag half) into LDS, linearly.
// 16x global_load_lds_dwordx4 (1 KB each); LDS dest wave-uniform + lane*16.
__device__ __forceinline__ void stage_row(const float* __restrict__ hr_row,
                                          const float* __restrict__ hi_row,
                                          float* lds_row, int lane) {
#pragma unroll
    for (int c = 0; c < 8; ++c)
        __builtin_amdgcn_global_load_lds(
            (guint*)(const void*)(hr_row + c * 256 + lane * 4),
            (suint*)(void*)(lds_row + c * 256), 16, 0, 0);
#pragma unroll
    for (int c = 0; c < 8; ++c)
        __builtin_amdgcn_global_load_lds(
            (guint*)(const void*)(hi_row + c * 256 + lane * 4),
            (suint*)(void*)(lds_row + 2048 + c * 256), 16, 0, 0);
}

// Wave-autonomous streaming flash, ZERO barriers. Each wave: private 3-deep
// 16KB LDS ring, counted s_waitcnt vmcnt(N) (never block-wide drain). Wave j
// (of Wb per batch) processes rows r == j (mod Wb) with defer-max online
// softmax; writes its own partial (4096 f32 + m,l). Requires 2D == 4096.
__global__ __launch_bounds__(192, 1) void flash_kernel(
    const float* __restrict__ hist_r,
    const float* __restrict__ hist_i,
    const float* __restrict__ q_ws,
    float* __restrict__ r_ws,
    float* __restrict__ ml_ws,
    int H, int Wb, int bpb) {
    const int t = threadIdx.x;
    const int lane = t & 63;
    const int wv = t >> 6;                       // 0..WVS-1
    const int b = blockIdx.x / bpb;
    const int j = (blockIdx.x - b * bpb) * WVS + wv;  // wave-in-batch, 0..Wb-1

    __shared__ float ring[WVS][DEPTH][4096];     // 144 KB, per-wave private

    // q into registers, then drain vmcnt so manual counts start from 0
    const float4* q4 = (const float4*)q_ws + (size_t)b * 1024;
    float4 qv[16];
#pragma unroll
    for (int k = 0; k < 16; ++k) qv[k] = q4[k * 64 + lane];
    asm volatile("s_waitcnt vmcnt(0)" ::: "memory");

    const int n = (H - j + Wb - 1) / Wb;         // rows for this wave
    const float* hr = hist_r + ((size_t)b * H + j) * 2048;
    const float* hi = hist_i + ((size_t)b * H + j) * 2048;
    float* myring = &ring[wv][0][0];

    float4 rv[16];
#pragma unroll
    for (int k = 0; k < 16; ++k) rv[k] = make_float4(0.f, 0.f, 0.f, 0.f);
    float m0 = -INFINITY, l = 0.f;
    const float inv_scale = 1.0f / 64.0f;        // 1/sqrt(2*2048), exact

    // prologue: stage up to DEPTH-1 rows ahead
    for (int i = 0; i < DEPTH - 1 && i < n; ++i)
        stage_row(hr + (size_t)i * Wb * 2048, hi + (size_t)i * Wb * 2048,
                  myring + (i % DEPTH) * 4096, lane);

    for (int i = 0; i < n; ++i) {
        if (i + DEPTH - 1 < n) {
            const size_t g = (size_t)(i + DEPTH - 1) * Wb * 2048;
            stage_row(hr + g, hi + g, myring + ((i + DEPTH - 1) % DEPTH) * 4096, lane);
        }
        // row i complete when outstanding <= 16 * (#rows staged after it)
        const int ahead = n - 1 - i;
        if (ahead >= 2)      asm volatile("s_waitcnt vmcnt(32)" ::: "memory");
        else if (ahead == 1) asm volatile("s_waitcnt vmcnt(16)" ::: "memory");
        else                 asm volatile("s_waitcnt vmcnt(0)"  ::: "memory");
        __builtin_amdgcn_sched_barrier(0);

        const float4* krow = (const float4*)(myring + (i % DEPTH) * 4096);
        float4 kv[16];
#pragma unroll
        for (int k = 0; k < 16; ++k) kv[k] = krow[k * 64 + lane];

        // 4 independent accumulators to break the FMA dependency chain
        float p0 = 0.f, p1 = 0.f, p2 = 0.f, p3 = 0.f;
#pragma unroll
        for (int k = 0; k < 4; ++k) {
            p0 += qv[4*k+0].x * kv[4*k+0].x + qv[4*k+0].y * kv[4*k+0].y +
                  qv[4*k+0].z * kv[4*k+0].z + qv[4*k+0].w * kv[4*k+0].w;
            p1 += qv[4*k+1].x * kv[4*k+1].x + qv[4*k+1].y * kv[4*k+1].y +
                  qv[4*k+1].z * kv[4*k+1].z + qv[4*k+1].w * kv[4*k+1].w;
            p2 += qv[4*k+2].x * kv[4*k+2].x + qv[4*k+2].y * kv[4*k+2].y +
                  qv[4*k+2].z * kv[4*k+2].z + qv[4*k+2].w * kv[4*k+2].w;
            p3 += qv[4*k+3].x * kv[4*k+3].x + qv[4*k+3].y * kv[4*k+3].y +
                  qv[4*k+3].z * kv[4*k+3].z + qv[4*k+3].w * kv[4*k+3].w;
        }
        float p = (p0 + p1) + (p2 + p3);
#pragma unroll
        for (int off = 32; off; off >>= 1) p += __shfl_xor(p, off);
        float sc = p * inv_scale;                // wave-uniform

        float d = sc - m0;
        float w;
        if (d > 8.0f) {                          // rare; first row: d=+inf
            float corr = __expf(-d);             // first row: exp(-inf) = 0
            l *= corr;
#pragma unroll
            for (int k = 0; k < 16; ++k) {
                rv[k].x *= corr; rv[k].y *= corr;
                rv[k].z *= corr; rv[k].w *= corr;
            }
            m0 = sc;
            w = 1.0f;
        } else {
            w = __expf(d);                       // bounded by e^8
        }
        l += w;
#pragma unroll
        for (int k = 0; k < 16; ++k) {
            rv[k].x = fmaf(w, kv[k].x, rv[k].x);
            rv[k].y = fmaf(w, kv[k].y, rv[k].y);
            rv[k].z = fmaf(w, kv[k].z, rv[k].z);
            rv[k].w = fmaf(w, kv[k].w, rv[k].w);
        }
    }

    // per-wave partial out (no cross-wave merge)
    const size_t pidx = (size_t)b * Wb + j;
    float4* ro = (float4*)r_ws + pidx * 1024;
#pragma unroll
    for (int k = 0; k < 16; ++k) ro[k * 64 + lane] = rv[k];
    if (lane == 0) {
        ml_ws[pidx * 2] = m0;
        ml_ws[pidx * 2 + 1] = l;
    }
}

// grid = B * (2D/256) blocks; each thread owns one output column.
__global__ void combine_kernel(const float* __restrict__ r_ws,
                               const float* __restrict__ ml_ws,
                               const float* __restrict__ ema,
                               const float* __restrict__ alpha_ptr,
                               float* __restrict__ out,
                               int D, int S) {
    const int twoD = 2 * D;
    const int nc = twoD / 256;
    const int b = blockIdx.x / nc;
    const int cb = blockIdx.x - b * nc;
    const int c = cb * 256 + threadIdx.x;

    const float* ml = ml_ws + (size_t)b * S * 2;
    float M = -INFINITY;
    for (int s = 0; s < S; ++s) M = fmaxf(M, ml[2 * s]);
    float L = 0.f;
    for (int s = 0; s < S; ++s) L += ml[2 * s + 1] * __expf(ml[2 * s] - M);

    float acc = 0.f;
    const float* rb = r_ws + (size_t)b * S * twoD + c;
    for (int s = 0; s < S; ++s)
        acc = fmaf(__expf(ml[2 * s] - M), rb[(size_t)s * twoD], acc);

    float a = 1.0f / (1.0f + __expf(-alpha_ptr[0]));  // sigmoid(alpha)
    float retrieved = acc / L;
    size_t o = (size_t)b * twoD + c;
    out[o] = a * retrieved + (1.0f - a) * ema[o];
}

extern "C" void kernel_launch(void* const* d_in, const int* in_sizes, int n_in,
                              void* d_out, int out_size, void* d_ws, size_t ws_size,
                              hipStream_t stream) {
    const float* cur_r  = (const float*)d_in[0];
    const float* cur_i  = (const float*)d_in[1];
    const float* hist_r = (const float*)d_in[2];
    const float* hist_i = (const float*)d_in[3];
    const float* ema    = (const float*)d_in[4];
    const float* w_q    = (const float*)d_in[5];
    const float* b_q    = (const float*)d_in[6];
    const float* alpha  = (const float*)d_in[7];
    const float* t      = (const float*)d_in[8];

    const int D = in_sizes[5];                 // 2048
    const int B = in_sizes[0] / D;             // 16
    const int H = in_sizes[2] / (B * D);       // 2048
    const int twoD = 2 * D;

    float* q_ws = (float*)d_ws;
    size_t q_elems = (size_t)B * twoD;

    // blocks per batch: 256 total blocks (1/CU), 3 waves each
    int bpb = 256 / B; if (bpb < 1) bpb = 1;   // 16
    while (bpb > 1) {
        int Wb = bpb * WVS;
        size_t need = (q_elems + (size_t)B * Wb * twoD + (size_t)B * Wb * 2) * sizeof(float);
        if (need <= ws_size) break;
        bpb >>= 1;
    }
    const int Wb = bpb * WVS;                  // waves (partials) per batch, 48
    float* r_ws = q_ws + q_elems;
    float* ml_ws = r_ws + (size_t)B * Wb * twoD;

    int qblocks = (B * twoD + 255) / 256;
    qgen_kernel<<<qblocks, 256, 0, stream>>>(cur_r, cur_i, w_q, b_q, t, q_ws, B, D);
    flash_kernel<<<B * bpb, WVS * 64, 0, stream>>>(hist_r, hist_i, q_ws, r_ws, ml_ws,
                                                   H, Wb, bpb);
    combine_kernel<<<B * (twoD / 256), 256, 0, stream>>>(r_ws, ml_ws, ema, alpha,
                                                         (float*)d_out, D, Wb);
}